// Round 1
// baseline (2303.673 us; speedup 1.0000x reference)
//
#include <hip/hip_runtime.h>

#define N_NODES 50000
#define N_EDGES 800000
#define F_IN    64
#define HEADS   4
#define CH      32
#define K_DIM   128
#define NEG     0.2f

__device__ __forceinline__ float lrelu(float x) { return x > 0.f ? x : NEG * x; }

// ---------------------------------------------------------------------------
// K0: fold We*ae -> v[o][f] (o=0..3 layer1 heads, 4..7 layer2 heads), and
//     cbias = dot(b2, lin_w) + lin_b
// ---------------------------------------------------------------------------
__global__ void k0_fold(const float* __restrict__ We1, const float* __restrict__ ae1,
                        const float* __restrict__ We2, const float* __restrict__ ae2,
                        const float* __restrict__ b2,  const float* __restrict__ linw,
                        const float* __restrict__ linb,
                        float* __restrict__ v, float* __restrict__ cbias) {
    int t = threadIdx.x; // 256 threads
    for (int idx = t; idx < 512; idx += 256) {
        int o = idx >> 6, f = idx & 63;
        const float* We = (o < 4) ? We1 : We2;
        const float* ae = (o < 4) ? ae1 : ae2;
        int h = o & 3;
        float s = 0.f;
        for (int c = 0; c < CH; ++c)
            s += We[f * K_DIM + h * CH + c] * ae[h * CH + c];
        v[o * 64 + f] = s;
    }
    if (t == 0) {
        float s = 0.f;
        for (int k = 0; k < K_DIM; ++k) s += b2[k] * linw[k];
        *cbias = s + linb[0];
    }
}

// ---------------------------------------------------------------------------
// K1: per-edge a_e for both layers (aer1/aer2), plus deg and scatter-sum of
//     a_e by dst (aloop*, divided by deg later -> self-loop a_e).
//     16 lanes per edge, float4 loads of edge_attr.
// ---------------------------------------------------------------------------
__global__ void __launch_bounds__(256)
k1_edge(const float* __restrict__ ea, const int* __restrict__ ei,
        const float* __restrict__ v,
        float* __restrict__ aer1, float* __restrict__ aer2,
        float* __restrict__ aloop1, float* __restrict__ aloop2,
        float* __restrict__ deg) {
    __shared__ float sv[512];
    int t = threadIdx.x;
    sv[t] = v[t];
    sv[t + 256] = v[t + 256];
    __syncthreads();
    int lane16 = t & 15;
    int eid = blockIdx.x * 16 + (t >> 4);
    if (eid >= N_EDGES) return;
    const float4 xv = *reinterpret_cast<const float4*>(ea + (size_t)eid * F_IN + lane16 * 4);
    float p[8];
#pragma unroll
    for (int o = 0; o < 8; ++o) {
        const float* vr = sv + o * 64 + lane16 * 4;
        p[o] = xv.x * vr[0] + xv.y * vr[1] + xv.z * vr[2] + xv.w * vr[3];
    }
#pragma unroll
    for (int m = 1; m < 16; m <<= 1) {
#pragma unroll
        for (int o = 0; o < 8; ++o) p[o] += __shfl_xor(p[o], m, 16);
    }
    if (lane16 == 0) {
        int dst = ei[N_EDGES + eid];
        *reinterpret_cast<float4*>(aer1 + (size_t)eid * 4) = make_float4(p[0], p[1], p[2], p[3]);
        *reinterpret_cast<float4*>(aer2 + (size_t)eid * 4) = make_float4(p[4], p[5], p[6], p[7]);
        atomicAdd(deg + dst, 1.f);
#pragma unroll
        for (int h = 0; h < 4; ++h) {
            atomicAdd(aloop1 + (size_t)dst * 4 + h, p[h]);
            atomicAdd(aloop2 + (size_t)dst * 4 + h, p[4 + h]);
        }
    }
}

// ---------------------------------------------------------------------------
// K2: aloop /= max(deg,1)
// ---------------------------------------------------------------------------
__global__ void k2_loopdiv(float* __restrict__ aloop1, float* __restrict__ aloop2,
                           const float* __restrict__ deg) {
    int i = blockIdx.x * 256 + threadIdx.x;
    if (i >= N_NODES * 4) return;
    float d = fmaxf(deg[i >> 2], 1.0f);
    aloop1[i] /= d;
    aloop2[i] /= d;
}

// ---------------------------------------------------------------------------
// K3: layer-1 node projection. 8 nodes/block, 128 threads (thread = out col).
//     Writes h1p [N,128], a_s, a_d.
// ---------------------------------------------------------------------------
__global__ void __launch_bounds__(128)
k3_proj1(const float* __restrict__ x, const float* __restrict__ W,
         const float* __restrict__ asf, const float* __restrict__ adf,
         float* __restrict__ hp, float* __restrict__ asn, float* __restrict__ adn) {
    __shared__ float sx[8 * F_IN];
    int k = threadIdx.x;
    int n0 = blockIdx.x * 8;
    for (int idx = k; idx < 8 * F_IN; idx += 128) sx[idx] = x[(size_t)n0 * F_IN + idx];
    __syncthreads();
    float acc[8] = {0, 0, 0, 0, 0, 0, 0, 0};
    for (int f = 0; f < F_IN; ++f) {
        float w = W[f * K_DIM + k];
#pragma unroll
        for (int i = 0; i < 8; ++i) acc[i] += sx[i * F_IN + f] * w;
    }
    float va = asf[k], vd = adf[k];
    int lane = k & 31, head = k >> 5;
#pragma unroll
    for (int i = 0; i < 8; ++i) {
        hp[(size_t)(n0 + i) * K_DIM + k] = acc[i];
        float s = acc[i] * va, d = acc[i] * vd;
#pragma unroll
        for (int m = 16; m > 0; m >>= 1) {
            s += __shfl_xor(s, m, 32);
            d += __shfl_xor(d, m, 32);
        }
        if (lane == 0) {
            asn[(size_t)(n0 + i) * 4 + head] = s;
            adn[(size_t)(n0 + i) * 4 + head] = d;
        }
    }
}

// ---------------------------------------------------------------------------
// K4: layer-1 softmax denominator (no max-shift; logits are O(1)).
//     idx < E: real edges. idx >= E: self-loops (a_e = aloop).
// ---------------------------------------------------------------------------
__global__ void __launch_bounds__(256)
k4_denom(const int* __restrict__ ei, const float* __restrict__ asn,
         const float* __restrict__ adn, const float* __restrict__ aer,
         const float* __restrict__ aloop, float* __restrict__ denom) {
    int idx = blockIdx.x * 256 + threadIdx.x;
    if (idx >= N_EDGES + N_NODES) return;
    int src, dst;
    float4 ae;
    if (idx < N_EDGES) {
        src = ei[idx];
        dst = ei[N_EDGES + idx];
        ae = *reinterpret_cast<const float4*>(aer + (size_t)idx * 4);
    } else {
        src = dst = idx - N_EDGES;
        ae = *reinterpret_cast<const float4*>(aloop + (size_t)src * 4);
    }
    float4 as = *reinterpret_cast<const float4*>(asn + (size_t)src * 4);
    float4 ad = *reinterpret_cast<const float4*>(adn + (size_t)dst * 4);
    float e0 = __expf(lrelu(as.x + ad.x + ae.x));
    float e1 = __expf(lrelu(as.y + ad.y + ae.y));
    float e2 = __expf(lrelu(as.z + ad.z + ae.z));
    float e3 = __expf(lrelu(as.w + ad.w + ae.w));
    float* dp = denom + (size_t)dst * 4;
    atomicAdd(dp + 0, e0);
    atomicAdd(dp + 1, e1);
    atomicAdd(dp + 2, e2);
    atomicAdd(dp + 3, e3);
}

// ---------------------------------------------------------------------------
// K5: layer-1 message scatter: outacc[dst] += ex * h1p[src].
//     32 lanes per edge (each lane: 4 consecutive floats, float4 gather).
// ---------------------------------------------------------------------------
__global__ void __launch_bounds__(256)
k5_agg(const int* __restrict__ ei, const float* __restrict__ asn,
       const float* __restrict__ adn, const float* __restrict__ aer,
       const float* __restrict__ hp, float* __restrict__ outacc) {
    int t = threadIdx.x;
    int sub = t & 31;
    int eid = blockIdx.x * 8 + (t >> 5);
    if (eid >= N_EDGES) return;
    int src = ei[eid], dst = ei[N_EDGES + eid];
    int head = sub >> 3;
    float ex = __expf(lrelu(asn[(size_t)src * 4 + head] + adn[(size_t)dst * 4 + head] +
                            aer[(size_t)eid * 4 + head]));
    float4 hv = *reinterpret_cast<const float4*>(hp + (size_t)src * K_DIM + sub * 4);
    float* op = outacc + (size_t)dst * K_DIM + sub * 4;
    atomicAdd(op + 0, ex * hv.x);
    atomicAdd(op + 1, ex * hv.y);
    atomicAdd(op + 2, ex * hv.z);
    atomicAdd(op + 3, ex * hv.w);
}

// ---------------------------------------------------------------------------
// K6: layer-1 finalize (in place on outacc): add self-loop message, divide by
//     denom, add bias, relu -> x2.
// ---------------------------------------------------------------------------
__global__ void __launch_bounds__(128)
k6_fin1(const float* __restrict__ asn, const float* __restrict__ adn,
        const float* __restrict__ aloop, const float* __restrict__ denom,
        const float* __restrict__ hp, const float* __restrict__ b1,
        float* __restrict__ xout) {
    int k = threadIdx.x;
    int n = blockIdx.x;
    int head = k >> 5;
    float exl = __expf(lrelu(asn[(size_t)n * 4 + head] + adn[(size_t)n * 4 + head] +
                             aloop[(size_t)n * 4 + head]));
    float den = denom[(size_t)n * 4 + head]; // includes self-loop term from K4
    size_t o = (size_t)n * K_DIM + k;
    float val = (xout[o] + exl * hp[o]) / den + b1[k];
    xout[o] = fmaxf(val, 0.f);
}

// ---------------------------------------------------------------------------
// K7: layer-2 node projection, reduced: only a_s2, a_d2, g = h2p . lin_w per
//     head are needed (h2p never materialized). 8 nodes/block, 128 threads.
// ---------------------------------------------------------------------------
__global__ void __launch_bounds__(128)
k7_proj2(const float* __restrict__ x2, const float* __restrict__ W2,
         const float* __restrict__ asf, const float* __restrict__ adf,
         const float* __restrict__ linw,
         float* __restrict__ asn, float* __restrict__ adn, float* __restrict__ g) {
    __shared__ float sx[8 * K_DIM];
    int k = threadIdx.x;
    int n0 = blockIdx.x * 8;
    for (int idx = k; idx < 8 * K_DIM; idx += 128) sx[idx] = x2[(size_t)n0 * K_DIM + idx];
    __syncthreads();
    float acc[8] = {0, 0, 0, 0, 0, 0, 0, 0};
    for (int f = 0; f < K_DIM; ++f) {
        float w = W2[f * K_DIM + k];
#pragma unroll
        for (int i = 0; i < 8; ++i) acc[i] += sx[i * K_DIM + f] * w;
    }
    float va = asf[k], vd = adf[k], vg = linw[k];
    int lane = k & 31, head = k >> 5;
#pragma unroll
    for (int i = 0; i < 8; ++i) {
        float s = acc[i] * va, d = acc[i] * vd, gg = acc[i] * vg;
#pragma unroll
        for (int m = 16; m > 0; m >>= 1) {
            s += __shfl_xor(s, m, 32);
            d += __shfl_xor(d, m, 32);
            gg += __shfl_xor(gg, m, 32);
        }
        if (lane == 0) {
            asn[(size_t)(n0 + i) * 4 + head] = s;
            adn[(size_t)(n0 + i) * 4 + head] = d;
            g[(size_t)(n0 + i) * 4 + head] = gg;
        }
    }
}

// ---------------------------------------------------------------------------
// K8: layer-2 fused edge pass: denom2[dst] += ex; accum2[dst] += ex*g[src].
// ---------------------------------------------------------------------------
__global__ void __launch_bounds__(256)
k8_l2(const int* __restrict__ ei, const float* __restrict__ asn,
      const float* __restrict__ adn, const float* __restrict__ aer,
      const float* __restrict__ g, float* __restrict__ denom,
      float* __restrict__ accum) {
    int e = blockIdx.x * 256 + threadIdx.x;
    if (e >= N_EDGES) return;
    int src = ei[e], dst = ei[N_EDGES + e];
    float4 as = *reinterpret_cast<const float4*>(asn + (size_t)src * 4);
    float4 ad = *reinterpret_cast<const float4*>(adn + (size_t)dst * 4);
    float4 ae = *reinterpret_cast<const float4*>(aer + (size_t)e * 4);
    float4 gv = *reinterpret_cast<const float4*>(g + (size_t)src * 4);
    float e0 = __expf(lrelu(as.x + ad.x + ae.x));
    float e1 = __expf(lrelu(as.y + ad.y + ae.y));
    float e2 = __expf(lrelu(as.z + ad.z + ae.z));
    float e3 = __expf(lrelu(as.w + ad.w + ae.w));
    float* dp = denom + (size_t)dst * 4;
    float* ap = accum + (size_t)dst * 4;
    atomicAdd(dp + 0, e0);
    atomicAdd(dp + 1, e1);
    atomicAdd(dp + 2, e2);
    atomicAdd(dp + 3, e3);
    atomicAdd(ap + 0, e0 * gv.x);
    atomicAdd(ap + 1, e1 * gv.y);
    atomicAdd(ap + 2, e2 * gv.z);
    atomicAdd(ap + 3, e3 * gv.w);
}

// ---------------------------------------------------------------------------
// K9: final output: out[n] = sum_h (accum + exl*g) / (denom + exl) + cbias
//     (self-loop folded in here; denom2 from K8 excludes it).
// ---------------------------------------------------------------------------
__global__ void __launch_bounds__(256)
k9_out(const float* __restrict__ asn, const float* __restrict__ adn,
       const float* __restrict__ aloop, const float* __restrict__ g,
       const float* __restrict__ denom, const float* __restrict__ accum,
       const float* __restrict__ cbias, float* __restrict__ out) {
    int n = blockIdx.x * 256 + threadIdx.x;
    if (n >= N_NODES) return;
    float4 as = *reinterpret_cast<const float4*>(asn + (size_t)n * 4);
    float4 ad = *reinterpret_cast<const float4*>(adn + (size_t)n * 4);
    float4 al = *reinterpret_cast<const float4*>(aloop + (size_t)n * 4);
    float4 gv = *reinterpret_cast<const float4*>(g + (size_t)n * 4);
    float4 dn = *reinterpret_cast<const float4*>(denom + (size_t)n * 4);
    float4 ac = *reinterpret_cast<const float4*>(accum + (size_t)n * 4);
    float r = cbias[0];
    float e;
    e = __expf(lrelu(as.x + ad.x + al.x)); r += (ac.x + e * gv.x) / (dn.x + e);
    e = __expf(lrelu(as.y + ad.y + al.y)); r += (ac.y + e * gv.y) / (dn.y + e);
    e = __expf(lrelu(as.z + ad.z + al.z)); r += (ac.z + e * gv.z) / (dn.z + e);
    e = __expf(lrelu(as.w + ad.w + al.w)); r += (ac.w + e * gv.w) / (dn.w + e);
    out[n] = r;
}

// ---------------------------------------------------------------------------
extern "C" void kernel_launch(void* const* d_in, const int* in_sizes, int n_in,
                              void* d_out, int out_size, void* d_ws, size_t ws_size,
                              hipStream_t stream) {
    (void)in_sizes; (void)n_in; (void)out_size;
    const float* x    = (const float*)d_in[0];
    const float* ea   = (const float*)d_in[1];
    const float* W1   = (const float*)d_in[2];
    const float* as1  = (const float*)d_in[3];
    const float* ad1  = (const float*)d_in[4];
    const float* We1  = (const float*)d_in[5];
    const float* ae1  = (const float*)d_in[6];
    const float* b1   = (const float*)d_in[7];
    const float* W2   = (const float*)d_in[8];
    const float* as2  = (const float*)d_in[9];
    const float* ad2  = (const float*)d_in[10];
    const float* We2  = (const float*)d_in[11];
    const float* ae2  = (const float*)d_in[12];
    const float* b2   = (const float*)d_in[13];
    const float* linw = (const float*)d_in[14];
    const float* linb = (const float*)d_in[15];
    const int*   ei   = (const int*)d_in[16];
    float* out = (float*)d_out;
    float* ws  = (float*)d_ws;

    size_t off = 0;
    float* aer1  = ws + off; off += (size_t)N_EDGES * 4;
    float* aer2  = ws + off; off += (size_t)N_EDGES * 4;
    float* h1p   = ws + off; off += (size_t)N_NODES * K_DIM;
    float* asn1  = ws + off; off += (size_t)N_NODES * 4;
    float* adn1  = ws + off; off += (size_t)N_NODES * 4;
    float* asn2  = ws + off; off += (size_t)N_NODES * 4;
    float* adn2  = ws + off; off += (size_t)N_NODES * 4;
    float* gbuf  = ws + off; off += (size_t)N_NODES * 4;
    float* vbuf  = ws + off; off += 512;
    float* cbias = ws + off; off += 64;
    // ---- zero-init region (one memset) ----
    float* zstart = ws + off;
    float* aloop1 = ws + off; off += (size_t)N_NODES * 4;
    float* aloop2 = ws + off; off += (size_t)N_NODES * 4;
    float* deg    = ws + off; off += (size_t)N_NODES;
    float* denom1 = ws + off; off += (size_t)N_NODES * 4;
    float* denom2 = ws + off; off += (size_t)N_NODES * 4;
    float* accum2 = ws + off; off += (size_t)N_NODES * 4;
    float* outacc = ws + off; off += (size_t)N_NODES * K_DIM; // becomes x2 after K6
    size_t zbytes = (size_t)(ws + off - zstart) * sizeof(float);

    if (ws_size < off * sizeof(float)) return; // workspace too small: fail visibly

    hipMemsetAsync(zstart, 0, zbytes, stream);

    k0_fold<<<1, 256, 0, stream>>>(We1, ae1, We2, ae2, b2, linw, linb, vbuf, cbias);
    k1_edge<<<N_EDGES / 16, 256, 0, stream>>>(ea, ei, vbuf, aer1, aer2, aloop1, aloop2, deg);
    k2_loopdiv<<<(N_NODES * 4 + 255) / 256, 256, 0, stream>>>(aloop1, aloop2, deg);
    k3_proj1<<<N_NODES / 8, 128, 0, stream>>>(x, W1, as1, ad1, h1p, asn1, adn1);
    k4_denom<<<(N_EDGES + N_NODES + 255) / 256, 256, 0, stream>>>(ei, asn1, adn1, aer1, aloop1, denom1);
    k5_agg<<<N_EDGES / 8, 256, 0, stream>>>(ei, asn1, adn1, aer1, h1p, outacc);
    k6_fin1<<<N_NODES, 128, 0, stream>>>(asn1, adn1, aloop1, denom1, h1p, b1, outacc);
    k7_proj2<<<N_NODES / 8, 128, 0, stream>>>(outacc, W2, as2, ad2, linw, asn2, adn2, gbuf);
    k8_l2<<<N_EDGES / 256, 256, 0, stream>>>(ei, asn2, adn2, aer2, gbuf, denom2, accum2);
    k9_out<<<(N_NODES + 255) / 256, 256, 0, stream>>>(asn2, adn2, aloop2, gbuf, denom2, accum2, cbias, out);
}

// Round 2
// 446.211 us; speedup vs baseline: 5.1627x; 5.1627x over previous
//
#include <hip/hip_runtime.h>

#define N_NODES 50000
#define N_EDGES 800000
#define F_IN    64
#define HEADS   4
#define CH      32
#define K_DIM   128
#define NEG     0.2f

__device__ __forceinline__ float lrelu(float x) { return x > 0.f ? x : NEG * x; }

// ---------------------------------------------------------------------------
// K0: fold We*ae -> v[o][f] (o=0..3 layer1 heads, 4..7 layer2 heads), and
//     cbias = dot(b2, lin_w) + lin_b
// ---------------------------------------------------------------------------
__global__ void k0_fold(const float* __restrict__ We1, const float* __restrict__ ae1,
                        const float* __restrict__ We2, const float* __restrict__ ae2,
                        const float* __restrict__ b2,  const float* __restrict__ linw,
                        const float* __restrict__ linb,
                        float* __restrict__ v, float* __restrict__ cbias) {
    int t = threadIdx.x; // 256 threads
    for (int idx = t; idx < 512; idx += 256) {
        int o = idx >> 6, f = idx & 63;
        const float* We = (o < 4) ? We1 : We2;
        const float* ae = (o < 4) ? ae1 : ae2;
        int h = o & 3;
        float s = 0.f;
        for (int c = 0; c < CH; ++c)
            s += We[f * K_DIM + h * CH + c] * ae[h * CH + c];
        v[o * 64 + f] = s;
    }
    if (t == 0) {
        float s = 0.f;
        for (int k = 0; k < K_DIM; ++k) s += b2[k] * linw[k];
        *cbias = s + linb[0];
    }
}

// ---------------------------------------------------------------------------
// K1: per-edge a_e for both layers (aer1/aer2) + int degree count (for CSR).
//     16 lanes per edge, float4 loads of edge_attr. No float atomics.
// ---------------------------------------------------------------------------
__global__ void __launch_bounds__(256)
k1_edge(const float* __restrict__ ea, const int* __restrict__ ei,
        const float* __restrict__ v,
        float* __restrict__ aer1, float* __restrict__ aer2,
        int* __restrict__ cnt) {
    __shared__ float sv[512];
    int t = threadIdx.x;
    sv[t] = v[t];
    sv[t + 256] = v[t + 256];
    __syncthreads();
    int lane16 = t & 15;
    int eid = blockIdx.x * 16 + (t >> 4);
    if (eid >= N_EDGES) return;
    const float4 xv = *reinterpret_cast<const float4*>(ea + (size_t)eid * F_IN + lane16 * 4);
    float p[8];
#pragma unroll
    for (int o = 0; o < 8; ++o) {
        const float* vr = sv + o * 64 + lane16 * 4;
        p[o] = xv.x * vr[0] + xv.y * vr[1] + xv.z * vr[2] + xv.w * vr[3];
    }
#pragma unroll
    for (int m = 1; m < 16; m <<= 1) {
#pragma unroll
        for (int o = 0; o < 8; ++o) p[o] += __shfl_xor(p[o], m, 16);
    }
    if (lane16 == 0) {
        int dst = ei[N_EDGES + eid];
        *reinterpret_cast<float4*>(aer1 + (size_t)eid * 4) = make_float4(p[0], p[1], p[2], p[3]);
        *reinterpret_cast<float4*>(aer2 + (size_t)eid * 4) = make_float4(p[4], p[5], p[6], p[7]);
        atomicAdd(cnt + dst, 1);
    }
}

// ---------------------------------------------------------------------------
// K2: exclusive prefix scan of cnt -> starts[N+1], cursor (single block).
// ---------------------------------------------------------------------------
__global__ void __launch_bounds__(1024)
k2_scan(const int* __restrict__ cnt, int* __restrict__ starts, int* __restrict__ cursor) {
    __shared__ int buf[1024];
    __shared__ int carry;
    int t = threadIdx.x;
    if (t == 0) carry = 0;
    __syncthreads();
    for (int base = 0; base < N_NODES; base += 1024) {
        int i = base + t;
        int vv = (i < N_NODES) ? cnt[i] : 0;
        buf[t] = vv;
        __syncthreads();
        for (int s = 1; s < 1024; s <<= 1) {
            int u = (t >= s) ? buf[t - s] : 0;
            __syncthreads();
            buf[t] += u;
            __syncthreads();
        }
        int excl = buf[t] - vv + carry;
        if (i < N_NODES) { starts[i] = excl; cursor[i] = excl; }
        __syncthreads();
        if (t == 0) carry += buf[1023];
        __syncthreads();
    }
    if (t == 0) starts[N_NODES] = carry;
}

// ---------------------------------------------------------------------------
// K3: scatter edges into dst-sorted lists (eid + src).
// ---------------------------------------------------------------------------
__global__ void __launch_bounds__(256)
k3_scatter(const int* __restrict__ ei, int* __restrict__ cursor,
           int* __restrict__ el_eid, int* __restrict__ el_src) {
    int e = blockIdx.x * 256 + threadIdx.x;
    if (e >= N_EDGES) return;
    int src = ei[e], dst = ei[N_EDGES + e];
    int pos = atomicAdd(cursor + dst, 1);
    el_eid[pos] = e;
    el_src[pos] = src;
}

// ---------------------------------------------------------------------------
// K4: layer-1 node projection. 8 nodes/block, 128 threads (thread = out col).
// ---------------------------------------------------------------------------
__global__ void __launch_bounds__(128)
k4_proj1(const float* __restrict__ x, const float* __restrict__ W,
         const float* __restrict__ asf, const float* __restrict__ adf,
         float* __restrict__ hp, float* __restrict__ asn, float* __restrict__ adn) {
    __shared__ float sx[8 * F_IN];
    int k = threadIdx.x;
    int n0 = blockIdx.x * 8;
    for (int idx = k; idx < 8 * F_IN; idx += 128) sx[idx] = x[(size_t)n0 * F_IN + idx];
    __syncthreads();
    float acc[8] = {0, 0, 0, 0, 0, 0, 0, 0};
    for (int f = 0; f < F_IN; ++f) {
        float w = W[f * K_DIM + k];
#pragma unroll
        for (int i = 0; i < 8; ++i) acc[i] += sx[i * F_IN + f] * w;
    }
    float va = asf[k], vd = adf[k];
    int lane = k & 31, head = k >> 5;
#pragma unroll
    for (int i = 0; i < 8; ++i) {
        hp[(size_t)(n0 + i) * K_DIM + k] = acc[i];
        float s = acc[i] * va, d = acc[i] * vd;
#pragma unroll
        for (int m = 16; m > 0; m >>= 1) {
            s += __shfl_xor(s, m, 32);
            d += __shfl_xor(d, m, 32);
        }
        if (lane == 0) {
            asn[(size_t)(n0 + i) * 4 + head] = s;
            adn[(size_t)(n0 + i) * 4 + head] = d;
        }
    }
}

// ---------------------------------------------------------------------------
// K5: layer-1 gather-side aggregation. One 64-lane wave per node; each lane
//     owns 2 output columns. Computes denom + message sum + self-loop (from
//     in-loop aer sum) + bias + relu in one pass. No atomics.
// ---------------------------------------------------------------------------
__global__ void __launch_bounds__(256)
k5_agg1(const int* __restrict__ starts, const int* __restrict__ el_eid,
        const int* __restrict__ el_src,
        const float* __restrict__ asn, const float* __restrict__ adn,
        const float* __restrict__ aer, const float* __restrict__ hp,
        const float* __restrict__ b1, float* __restrict__ x2) {
    int t = threadIdx.x;
    int lane = t & 63;
    int node = blockIdx.x * 4 + (t >> 6);
    if (node >= N_NODES) return;
    int s = starts[node], e = starts[node + 1];
    int head = lane >> 4;             // col pair = lane*2; head = (lane*2)>>5
    float adv = adn[(size_t)node * 4 + head];
    float accx = 0.f, accy = 0.f, dsum = 0.f, aesum = 0.f;
    for (int j = s; j < e; ++j) {
        int eid = el_eid[j];
        int src = el_src[j];
        float ae = aer[(size_t)eid * 4 + head];
        float av = asn[(size_t)src * 4 + head];
        float ex = __expf(lrelu(av + adv + ae));
        float2 hv = *reinterpret_cast<const float2*>(hp + (size_t)src * K_DIM + lane * 2);
        accx += ex * hv.x;
        accy += ex * hv.y;
        dsum += ex;
        aesum += ae;
    }
    float deg = (float)(e - s);
    float al = aesum / fmaxf(deg, 1.f);           // self-loop a_e = mean of incoming
    float exl = __expf(lrelu(asn[(size_t)node * 4 + head] + adv + al));
    float2 hv = *reinterpret_cast<const float2*>(hp + (size_t)node * K_DIM + lane * 2);
    accx += exl * hv.x;
    accy += exl * hv.y;
    dsum += exl;
    float2 bb = *reinterpret_cast<const float2*>(b1 + lane * 2);
    float2 o;
    o.x = fmaxf(accx / dsum + bb.x, 0.f);
    o.y = fmaxf(accy / dsum + bb.y, 0.f);
    *reinterpret_cast<float2*>(x2 + (size_t)node * K_DIM + lane * 2) = o;
}

// ---------------------------------------------------------------------------
// K6: layer-2 node projection, reduced: a_s2, a_d2, g = h2p . lin_w per head.
// ---------------------------------------------------------------------------
__global__ void __launch_bounds__(128)
k6_proj2(const float* __restrict__ x2, const float* __restrict__ W2,
         const float* __restrict__ asf, const float* __restrict__ adf,
         const float* __restrict__ linw,
         float* __restrict__ asn, float* __restrict__ adn, float* __restrict__ g) {
    __shared__ float sx[8 * K_DIM];
    int k = threadIdx.x;
    int n0 = blockIdx.x * 8;
    for (int idx = k; idx < 8 * K_DIM; idx += 128) sx[idx] = x2[(size_t)n0 * K_DIM + idx];
    __syncthreads();
    float acc[8] = {0, 0, 0, 0, 0, 0, 0, 0};
    for (int f = 0; f < K_DIM; ++f) {
        float w = W2[f * K_DIM + k];
#pragma unroll
        for (int i = 0; i < 8; ++i) acc[i] += sx[i * K_DIM + f] * w;
    }
    float va = asf[k], vd = adf[k], vg = linw[k];
    int lane = k & 31, head = k >> 5;
#pragma unroll
    for (int i = 0; i < 8; ++i) {
        float s = acc[i] * va, d = acc[i] * vd, gg = acc[i] * vg;
#pragma unroll
        for (int m = 16; m > 0; m >>= 1) {
            s += __shfl_xor(s, m, 32);
            d += __shfl_xor(d, m, 32);
            gg += __shfl_xor(gg, m, 32);
        }
        if (lane == 0) {
            asn[(size_t)(n0 + i) * 4 + head] = s;
            adn[(size_t)(n0 + i) * 4 + head] = d;
            g[(size_t)(n0 + i) * 4 + head] = gg;
        }
    }
}

// ---------------------------------------------------------------------------
// K7: layer-2 gather-side: thread per (node,head). denom2 + sum ex*g + self
//     loop, then 4-lane reduce -> out[n]. No atomics.
// ---------------------------------------------------------------------------
__global__ void __launch_bounds__(256)
k7_l2(const int* __restrict__ starts, const int* __restrict__ el_eid,
      const int* __restrict__ el_src,
      const float* __restrict__ asn, const float* __restrict__ adn,
      const float* __restrict__ aer, const float* __restrict__ g,
      const float* __restrict__ cbias, float* __restrict__ out) {
    int idx = blockIdx.x * 256 + threadIdx.x;
    if (idx >= N_NODES * 4) return;
    int n = idx >> 2, h = idx & 3;
    int s = starts[n], e = starts[n + 1];
    float adv = adn[idx];
    float dsum = 0.f, gsum = 0.f, aesum = 0.f;
    for (int j = s; j < e; ++j) {
        int eid = el_eid[j];
        int src = el_src[j];
        float ae = aer[(size_t)eid * 4 + h];
        float ex = __expf(lrelu(asn[(size_t)src * 4 + h] + adv + ae));
        dsum += ex;
        gsum += ex * g[(size_t)src * 4 + h];
        aesum += ae;
    }
    float al = aesum / fmaxf((float)(e - s), 1.f);
    float exl = __expf(lrelu(asn[idx] + adv + al));
    dsum += exl;
    gsum += exl * g[idx];
    float r = gsum / dsum;
    r += __shfl_xor(r, 1, 4);
    r += __shfl_xor(r, 2, 4);
    if (h == 0) out[n] = r + cbias[0];
}

// ---------------------------------------------------------------------------
extern "C" void kernel_launch(void* const* d_in, const int* in_sizes, int n_in,
                              void* d_out, int out_size, void* d_ws, size_t ws_size,
                              hipStream_t stream) {
    (void)in_sizes; (void)n_in; (void)out_size;
    const float* x    = (const float*)d_in[0];
    const float* ea   = (const float*)d_in[1];
    const float* W1   = (const float*)d_in[2];
    const float* as1  = (const float*)d_in[3];
    const float* ad1  = (const float*)d_in[4];
    const float* We1  = (const float*)d_in[5];
    const float* ae1  = (const float*)d_in[6];
    const float* b1   = (const float*)d_in[7];
    const float* W2   = (const float*)d_in[8];
    const float* as2  = (const float*)d_in[9];
    const float* ad2  = (const float*)d_in[10];
    const float* We2  = (const float*)d_in[11];
    const float* ae2  = (const float*)d_in[12];
    const float* b2   = (const float*)d_in[13];
    const float* linw = (const float*)d_in[14];
    const float* linb = (const float*)d_in[15];
    const int*   ei   = (const int*)d_in[16];
    float* out = (float*)d_out;
    float* ws  = (float*)d_ws;

    size_t off = 0;
    float* aer1  = ws + off; off += (size_t)N_EDGES * 4;
    float* aer2  = ws + off; off += (size_t)N_EDGES * 4;
    float* h1p   = ws + off; off += (size_t)N_NODES * K_DIM;
    float* x2    = ws + off; off += (size_t)N_NODES * K_DIM;
    float* asn1  = ws + off; off += (size_t)N_NODES * 4;
    float* adn1  = ws + off; off += (size_t)N_NODES * 4;
    float* asn2  = ws + off; off += (size_t)N_NODES * 4;
    float* adn2  = ws + off; off += (size_t)N_NODES * 4;
    float* gbuf  = ws + off; off += (size_t)N_NODES * 4;
    float* vbuf  = ws + off; off += 512;
    float* cbias = ws + off; off += 64;
    int* starts  = (int*)(ws + off); off += (size_t)N_NODES + 8;
    int* cursor  = (int*)(ws + off); off += (size_t)N_NODES;
    int* el_eid  = (int*)(ws + off); off += (size_t)N_EDGES;
    int* el_src  = (int*)(ws + off); off += (size_t)N_EDGES;
    // ---- zero-init region ----
    int* cnt     = (int*)(ws + off); off += (size_t)N_NODES;

    if (ws_size < off * sizeof(float)) return; // workspace too small: fail visibly

    hipMemsetAsync(cnt, 0, N_NODES * sizeof(int), stream);

    k0_fold<<<1, 256, 0, stream>>>(We1, ae1, We2, ae2, b2, linw, linb, vbuf, cbias);
    k1_edge<<<N_EDGES / 16, 256, 0, stream>>>(ea, ei, vbuf, aer1, aer2, cnt);
    k2_scan<<<1, 1024, 0, stream>>>(cnt, starts, cursor);
    k3_scatter<<<(N_EDGES + 255) / 256, 256, 0, stream>>>(ei, cursor, el_eid, el_src);
    k4_proj1<<<N_NODES / 8, 128, 0, stream>>>(x, W1, as1, ad1, h1p, asn1, adn1);
    k5_agg1<<<(N_NODES + 3) / 4, 256, 0, stream>>>(starts, el_eid, el_src,
                                                   asn1, adn1, aer1, h1p, b1, x2);
    k6_proj2<<<N_NODES / 8, 128, 0, stream>>>(x2, W2, as2, ad2, linw, asn2, adn2, gbuf);
    k7_l2<<<(N_NODES * 4 + 255) / 256, 256, 0, stream>>>(starts, el_eid, el_src,
                                                         asn2, adn2, aer2, gbuf, cbias, out);
}

// Round 3
// 386.429 us; speedup vs baseline: 5.9614x; 1.1547x over previous
//
#include <hip/hip_runtime.h>

#define N_NODES 50000
#define N_EDGES 800000
#define F_IN    64
#define HEADS   4
#define CH      32
#define K_DIM   128
#define NEG     0.2f

__device__ __forceinline__ float lrelu(float x) { return x > 0.f ? x : NEG * x; }

// ---------------------------------------------------------------------------
// K0: fold We*ae -> v[o][f] (o=0..3 layer1 heads, 4..7 layer2 heads), and
//     cbias = dot(b2, lin_w) + lin_b
// ---------------------------------------------------------------------------
__global__ void k0_fold(const float* __restrict__ We1, const float* __restrict__ ae1,
                        const float* __restrict__ We2, const float* __restrict__ ae2,
                        const float* __restrict__ b2,  const float* __restrict__ linw,
                        const float* __restrict__ linb,
                        float* __restrict__ v, float* __restrict__ cbias) {
    int t = threadIdx.x; // 256 threads
    for (int idx = t; idx < 512; idx += 256) {
        int o = idx >> 6, f = idx & 63;
        const float* We = (o < 4) ? We1 : We2;
        const float* ae = (o < 4) ? ae1 : ae2;
        int h = o & 3;
        float s = 0.f;
        for (int c = 0; c < CH; ++c)
            s += We[f * K_DIM + h * CH + c] * ae[h * CH + c];
        v[o * 64 + f] = s;
    }
    if (t == 0) {
        float s = 0.f;
        for (int k = 0; k < K_DIM; ++k) s += b2[k] * linw[k];
        *cbias = s + linb[0];
    }
}

// ---------------------------------------------------------------------------
// Kc: degree count from ei only (3.2 MB read).
// ---------------------------------------------------------------------------
__global__ void __launch_bounds__(256)
kc_count(const int* __restrict__ ei, int* __restrict__ cnt) {
    int e = blockIdx.x * 256 + threadIdx.x;
    if (e >= N_EDGES) return;
    atomicAdd(cnt + ei[N_EDGES + e], 1);
}

// ---------------------------------------------------------------------------
// K2: exclusive prefix scan of cnt -> starts[N+1], cursor. Single block,
//     shuffle-based (wave scan + wave-partial scan), ~3 barriers per chunk.
// ---------------------------------------------------------------------------
__global__ void __launch_bounds__(1024)
k2_scan(const int* __restrict__ cnt, int* __restrict__ starts, int* __restrict__ cursor) {
    __shared__ int wsum[16];
    __shared__ int s_carry;
    int t = threadIdx.x;
    int lane = t & 63, wid = t >> 6;
    if (t == 0) s_carry = 0;
    __syncthreads();
    for (int base = 0; base < N_NODES; base += 1024) {
        int i = base + t;
        int v = (i < N_NODES) ? cnt[i] : 0;
        int sc = v; // inclusive wave scan
#pragma unroll
        for (int s = 1; s < 64; s <<= 1) {
            int u = __shfl_up(sc, s, 64);
            if (lane >= s) sc += u;
        }
        if (lane == 63) wsum[wid] = sc;
        __syncthreads();
        if (wid == 0 && lane < 16) {
            int ws = wsum[lane];
#pragma unroll
            for (int s = 1; s < 16; s <<= 1) {
                int u = __shfl_up(ws, s, 64);
                if (lane >= s) ws += u;
            }
            wsum[lane] = ws; // inclusive partials
        }
        __syncthreads();
        int carry = s_carry;
        int woff = (wid == 0) ? 0 : wsum[wid - 1];
        int excl = carry + woff + sc - v;
        if (i < N_NODES) { starts[i] = excl; cursor[i] = excl; }
        __syncthreads();
        if (t == 0) s_carry = carry + wsum[15];
    }
    __syncthreads();
    if (t == 0) starts[N_NODES] = s_carry;
}

// ---------------------------------------------------------------------------
// K1: per-edge a_e for both layers, scattered DIRECTLY into dst-sorted lists
//     (el_src, el_ae1, el_ae2). 16 lanes per edge, float4 edge_attr loads,
//     xor-butterfly reduce (all lanes hold sums), leader does the scatter.
// ---------------------------------------------------------------------------
__global__ void __launch_bounds__(256)
k1_edge(const float* __restrict__ ea, const int* __restrict__ ei,
        const float* __restrict__ v, int* __restrict__ cursor,
        int* __restrict__ el_src, float4* __restrict__ el_ae1,
        float4* __restrict__ el_ae2) {
    __shared__ float sv[512];
    int t = threadIdx.x;
    sv[t] = v[t];
    sv[t + 256] = v[t + 256];
    __syncthreads();
    int lane16 = t & 15;
    int eid = blockIdx.x * 16 + (t >> 4);
    if (eid >= N_EDGES) return;
    const float4 xv = *reinterpret_cast<const float4*>(ea + (size_t)eid * F_IN + lane16 * 4);
    float p[8];
#pragma unroll
    for (int o = 0; o < 8; ++o) {
        const float* vr = sv + o * 64 + lane16 * 4;
        p[o] = xv.x * vr[0] + xv.y * vr[1] + xv.z * vr[2] + xv.w * vr[3];
    }
#pragma unroll
    for (int m = 1; m < 16; m <<= 1) {
#pragma unroll
        for (int o = 0; o < 8; ++o) p[o] += __shfl_xor(p[o], m, 16);
    }
    if (lane16 == 0) {
        int src = ei[eid];
        int dst = ei[N_EDGES + eid];
        int pos = atomicAdd(cursor + dst, 1);
        el_src[pos] = src;
        el_ae1[pos] = make_float4(p[0], p[1], p[2], p[3]);
        el_ae2[pos] = make_float4(p[4], p[5], p[6], p[7]);
    }
}

// ---------------------------------------------------------------------------
// K4: layer-1 node projection. 8 nodes/block, 128 threads (thread = out col).
// ---------------------------------------------------------------------------
__global__ void __launch_bounds__(128)
k4_proj1(const float* __restrict__ x, const float* __restrict__ W,
         const float* __restrict__ asf, const float* __restrict__ adf,
         float* __restrict__ hp, float* __restrict__ asn, float* __restrict__ adn) {
    __shared__ float sx[8 * F_IN];
    int k = threadIdx.x;
    int n0 = blockIdx.x * 8;
    for (int idx = k; idx < 8 * F_IN; idx += 128) sx[idx] = x[(size_t)n0 * F_IN + idx];
    __syncthreads();
    float acc[8] = {0, 0, 0, 0, 0, 0, 0, 0};
    for (int f = 0; f < F_IN; ++f) {
        float w = W[f * K_DIM + k];
#pragma unroll
        for (int i = 0; i < 8; ++i) acc[i] += sx[i * F_IN + f] * w;
    }
    float va = asf[k], vd = adf[k];
    int lane = k & 31, head = k >> 5;
#pragma unroll
    for (int i = 0; i < 8; ++i) {
        hp[(size_t)(n0 + i) * K_DIM + k] = acc[i];
        float s = acc[i] * va, d = acc[i] * vd;
#pragma unroll
        for (int m = 16; m > 0; m >>= 1) {
            s += __shfl_xor(s, m, 32);
            d += __shfl_xor(d, m, 32);
        }
        if (lane == 0) {
            asn[(size_t)(n0 + i) * 4 + head] = s;
            adn[(size_t)(n0 + i) * 4 + head] = d;
        }
    }
}

// ---------------------------------------------------------------------------
// K5: layer-1 gather aggregation. One 64-lane wave per node; lane owns 2
//     output columns. Sequential el reads, broadcast asn gathers, 512 B/edge
//     coalesced h1p row gather. Self-loop from in-loop ae mean. No atomics.
// ---------------------------------------------------------------------------
__global__ void __launch_bounds__(256)
k5_agg1(const int* __restrict__ starts, const int* __restrict__ el_src,
        const float* __restrict__ el_ae1,
        const float* __restrict__ asn, const float* __restrict__ adn,
        const float* __restrict__ hp, const float* __restrict__ b1,
        float* __restrict__ x2) {
    int t = threadIdx.x;
    int lane = t & 63;
    int node = blockIdx.x * 4 + (t >> 6);
    if (node >= N_NODES) return;
    int s = starts[node], e = starts[node + 1];
    int head = lane >> 4; // col pair = lane*2; head = (lane*2)>>5
    float adv = adn[(size_t)node * 4 + head];
    float accx = 0.f, accy = 0.f, dsum = 0.f, aesum = 0.f;
    for (int j = s; j < e; ++j) {
        int src = el_src[j];
        float ae = el_ae1[(size_t)j * 4 + head];
        float av = asn[(size_t)src * 4 + head];
        float ex = __expf(lrelu(av + adv + ae));
        float2 hv = *reinterpret_cast<const float2*>(hp + (size_t)src * K_DIM + lane * 2);
        accx += ex * hv.x;
        accy += ex * hv.y;
        dsum += ex;
        aesum += ae;
    }
    float deg = (float)(e - s);
    float al = aesum / fmaxf(deg, 1.f); // self-loop a_e = mean of incoming
    float exl = __expf(lrelu(asn[(size_t)node * 4 + head] + adv + al));
    float2 hv = *reinterpret_cast<const float2*>(hp + (size_t)node * K_DIM + lane * 2);
    accx += exl * hv.x;
    accy += exl * hv.y;
    dsum += exl;
    float2 bb = *reinterpret_cast<const float2*>(b1 + lane * 2);
    float2 o;
    o.x = fmaxf(accx / dsum + bb.x, 0.f);
    o.y = fmaxf(accy / dsum + bb.y, 0.f);
    *reinterpret_cast<float2*>(x2 + (size_t)node * K_DIM + lane * 2) = o;
}

// ---------------------------------------------------------------------------
// K6: layer-2 node projection, reduced. Writes packed asg[n] = {a_s2[4], g[4]}
//     (one 32 B record per node -> single-line gathers in K7) + adn2.
// ---------------------------------------------------------------------------
__global__ void __launch_bounds__(128)
k6_proj2(const float* __restrict__ x2, const float* __restrict__ W2,
         const float* __restrict__ asf, const float* __restrict__ adf,
         const float* __restrict__ linw,
         float* __restrict__ asg, float* __restrict__ adn) {
    __shared__ float sx[8 * K_DIM];
    int k = threadIdx.x;
    int n0 = blockIdx.x * 8;
    for (int idx = k; idx < 8 * K_DIM; idx += 128) sx[idx] = x2[(size_t)n0 * K_DIM + idx];
    __syncthreads();
    float acc[8] = {0, 0, 0, 0, 0, 0, 0, 0};
    for (int f = 0; f < K_DIM; ++f) {
        float w = W2[f * K_DIM + k];
#pragma unroll
        for (int i = 0; i < 8; ++i) acc[i] += sx[i * K_DIM + f] * w;
    }
    float va = asf[k], vd = adf[k], vg = linw[k];
    int lane = k & 31, head = k >> 5;
#pragma unroll
    for (int i = 0; i < 8; ++i) {
        float s = acc[i] * va, d = acc[i] * vd, gg = acc[i] * vg;
#pragma unroll
        for (int m = 16; m > 0; m >>= 1) {
            s += __shfl_xor(s, m, 32);
            d += __shfl_xor(d, m, 32);
            gg += __shfl_xor(gg, m, 32);
        }
        if (lane == 0) {
            asg[(size_t)(n0 + i) * 8 + head] = s;
            asg[(size_t)(n0 + i) * 8 + 4 + head] = gg;
            adn[(size_t)(n0 + i) * 4 + head] = d;
        }
    }
}

// ---------------------------------------------------------------------------
// K7: layer-2 gather: 16-lane group per node, lanes stride the edge list
//     (coalesced), float4 per-head accumulation, width-16 shuffle reduce.
// ---------------------------------------------------------------------------
__global__ void __launch_bounds__(256)
k7_l2(const int* __restrict__ starts, const int* __restrict__ el_src,
      const float4* __restrict__ el_ae2, const float* __restrict__ asg,
      const float* __restrict__ adn, const float* __restrict__ cbias,
      float* __restrict__ out) {
    int t = threadIdx.x;
    int g16 = t & 15;
    int node = blockIdx.x * 16 + (t >> 4);
    if (node >= N_NODES) return;
    int s = starts[node], e = starts[node + 1];
    float4 ad4 = *reinterpret_cast<const float4*>(adn + (size_t)node * 4);
    float4 dsum = make_float4(0, 0, 0, 0);
    float4 gsum = make_float4(0, 0, 0, 0);
    float4 aesum = make_float4(0, 0, 0, 0);
    for (int j = s + g16; j < e; j += 16) {
        int src = el_src[j];
        float4 ae4 = el_ae2[j];
        const float* ap = asg + (size_t)src * 8;
        float4 as4 = *reinterpret_cast<const float4*>(ap);
        float4 g4  = *reinterpret_cast<const float4*>(ap + 4);
        float e0 = __expf(lrelu(as4.x + ad4.x + ae4.x));
        float e1 = __expf(lrelu(as4.y + ad4.y + ae4.y));
        float e2 = __expf(lrelu(as4.z + ad4.z + ae4.z));
        float e3 = __expf(lrelu(as4.w + ad4.w + ae4.w));
        dsum.x += e0; dsum.y += e1; dsum.z += e2; dsum.w += e3;
        gsum.x += e0 * g4.x; gsum.y += e1 * g4.y; gsum.z += e2 * g4.z; gsum.w += e3 * g4.w;
        aesum.x += ae4.x; aesum.y += ae4.y; aesum.z += ae4.z; aesum.w += ae4.w;
    }
#pragma unroll
    for (int m = 1; m < 16; m <<= 1) {
        dsum.x += __shfl_xor(dsum.x, m, 16);  dsum.y += __shfl_xor(dsum.y, m, 16);
        dsum.z += __shfl_xor(dsum.z, m, 16);  dsum.w += __shfl_xor(dsum.w, m, 16);
        gsum.x += __shfl_xor(gsum.x, m, 16);  gsum.y += __shfl_xor(gsum.y, m, 16);
        gsum.z += __shfl_xor(gsum.z, m, 16);  gsum.w += __shfl_xor(gsum.w, m, 16);
        aesum.x += __shfl_xor(aesum.x, m, 16); aesum.y += __shfl_xor(aesum.y, m, 16);
        aesum.z += __shfl_xor(aesum.z, m, 16); aesum.w += __shfl_xor(aesum.w, m, 16);
    }
    if (g16 == 0) {
        float deg = fmaxf((float)(e - s), 1.f);
        const float* ap = asg + (size_t)node * 8;
        float4 mas = *reinterpret_cast<const float4*>(ap);
        float4 mg  = *reinterpret_cast<const float4*>(ap + 4);
        float r = cbias[0];
        float e0;
        e0 = __expf(lrelu(mas.x + ad4.x + aesum.x / deg)); r += (gsum.x + e0 * mg.x) / (dsum.x + e0);
        e0 = __expf(lrelu(mas.y + ad4.y + aesum.y / deg)); r += (gsum.y + e0 * mg.y) / (dsum.y + e0);
        e0 = __expf(lrelu(mas.z + ad4.z + aesum.z / deg)); r += (gsum.z + e0 * mg.z) / (dsum.z + e0);
        e0 = __expf(lrelu(mas.w + ad4.w + aesum.w / deg)); r += (gsum.w + e0 * mg.w) / (dsum.w + e0);
        out[node] = r;
    }
}

// ---------------------------------------------------------------------------
extern "C" void kernel_launch(void* const* d_in, const int* in_sizes, int n_in,
                              void* d_out, int out_size, void* d_ws, size_t ws_size,
                              hipStream_t stream) {
    (void)in_sizes; (void)n_in; (void)out_size;
    const float* x    = (const float*)d_in[0];
    const float* ea   = (const float*)d_in[1];
    const float* W1   = (const float*)d_in[2];
    const float* as1  = (const float*)d_in[3];
    const float* ad1  = (const float*)d_in[4];
    const float* We1  = (const float*)d_in[5];
    const float* ae1  = (const float*)d_in[6];
    const float* b1   = (const float*)d_in[7];
    const float* W2   = (const float*)d_in[8];
    const float* as2  = (const float*)d_in[9];
    const float* ad2  = (const float*)d_in[10];
    const float* We2  = (const float*)d_in[11];
    const float* ae2  = (const float*)d_in[12];
    const float* b2   = (const float*)d_in[13];
    const float* linw = (const float*)d_in[14];
    const float* linb = (const float*)d_in[15];
    const int*   ei   = (const int*)d_in[16];
    float* out = (float*)d_out;
    float* ws  = (float*)d_ws;

    size_t off = 0;
    float* h1p   = ws + off; off += (size_t)N_NODES * K_DIM;
    float* x2    = ws + off; off += (size_t)N_NODES * K_DIM;
    float* asn1  = ws + off; off += (size_t)N_NODES * 4;
    float* adn1  = ws + off; off += (size_t)N_NODES * 4;
    float* asg2  = ws + off; off += (size_t)N_NODES * 8;
    float* adn2  = ws + off; off += (size_t)N_NODES * 4;
    float* vbuf  = ws + off; off += 512;
    float* cbias = ws + off; off += 64;
    int* starts  = (int*)(ws + off); off += (size_t)N_NODES + 8;
    int* cursor  = (int*)(ws + off); off += (size_t)N_NODES;
    int* el_src  = (int*)(ws + off); off += (size_t)N_EDGES;
    float* elae1 = ws + off; off += (size_t)N_EDGES * 4;
    float* elae2 = ws + off; off += (size_t)N_EDGES * 4;
    int* cnt     = (int*)(ws + off); off += (size_t)N_NODES;

    if (ws_size < off * sizeof(float)) return; // workspace too small: fail visibly

    hipMemsetAsync(cnt, 0, N_NODES * sizeof(int), stream);

    k0_fold<<<1, 256, 0, stream>>>(We1, ae1, We2, ae2, b2, linw, linb, vbuf, cbias);
    kc_count<<<(N_EDGES + 255) / 256, 256, 0, stream>>>(ei, cnt);
    k2_scan<<<1, 1024, 0, stream>>>(cnt, starts, cursor);
    k1_edge<<<N_EDGES / 16, 256, 0, stream>>>(ea, ei, vbuf, cursor, el_src,
                                              (float4*)elae1, (float4*)elae2);
    k4_proj1<<<N_NODES / 8, 128, 0, stream>>>(x, W1, as1, ad1, h1p, asn1, adn1);
    k5_agg1<<<(N_NODES + 3) / 4, 256, 0, stream>>>(starts, el_src, elae1,
                                                   asn1, adn1, h1p, b1, x2);
    k6_proj2<<<N_NODES / 8, 128, 0, stream>>>(x2, W2, as2, ad2, linw, asg2, adn2);
    k7_l2<<<(N_NODES + 15) / 16, 256, 0, stream>>>(starts, el_src, (const float4*)elae2,
                                                   asg2, adn2, cbias, out);
}